// Round 4
// baseline (250.567 us; speedup 1.0000x reference)
//
#include <hip/hip_runtime.h>
#include <hip/hip_cooperative_groups.h>
#include <stdint.h>

namespace cg = cooperative_groups;

#define N_ANCH 4096
#define NCLS 8
#define CN (N_ANCH * NCLS)
#define SCORE_TH 0.5f
#define IOU_TH 0.5f
#define KSEL 11
#define MAX_DET 100
#define CAND_CAP 4096
#define TILE 128
#define TPC (N_ANCH / TILE)          // 32 i/j tiles per class (worst case)
#define NTRI (TPC * (TPC + 1) / 2)   // 528 triangular tiles per class

__device__ __forceinline__ float iou_f(float4 a, float areaA, float4 b, float areaB) {
    float x1 = fmaxf(a.x, b.x);
    float y1 = fmaxf(a.y, b.y);
    float x2 = fminf(a.z, b.z);
    float y2 = fminf(a.w, b.w);
    float wid = x2 - x1 + 1.0f;
    float hei = y2 - y1 + 1.0f;
    float inter = wid * hei;
    float den = areaA + areaB - inter;
    float ov = (den == 0.0f) ? 0.0f : (inter / den);
    if (wid <= 0.0f || hei <= 0.0f) ov = 0.0f;
    return ov;
}

// K1: transpose inputs to per-class SoA, precompute areas, zero surv/hist/gcnt/minRank
__global__ void k_prep(const float* __restrict__ boxes, const float* __restrict__ cls,
                       const float* __restrict__ conf,
                       float4* boxesT, float* areaT, float* scoresT, float* confT,
                       int* surv, int* hist, int* gcnt, int* minRank) {
    int t = blockIdx.x * blockDim.x + threadIdx.x;
    if (t >= CN) return;
    int n = t >> 3;  // anchor
    int c = t & 7;   // class
    int p = c * N_ANCH + n;
    scoresT[p] = cls[t];
    confT[p] = conf[t];
    float4 b = reinterpret_cast<const float4*>(boxes)[t];
    boxesT[p] = b;
    areaT[p] = (b.z - b.x + 1.0f) * (b.w - b.y + 1.0f);
    surv[t] = 0;
    minRank[t] = 0x7FFFFFFF;
    if (t < 1024) hist[t] = 0;
    if (t == 1024) *gcnt = 0;
}

// K2: single-pass per-class compaction (8 blocks x 1024 threads, 4 anchors/thread)
// also emits rank-compacted vBox/vArea so later kernels read coalesced.
__global__ void __launch_bounds__(1024) k_validlist(const float* __restrict__ scoresT,
                                                    const float4* __restrict__ boxesT,
                                                    const float* __restrict__ areaT,
                                                    int* validList, float4* vBox,
                                                    float* vArea, int* mVal) {
    int c = blockIdx.x;
    int tid = threadIdx.x;
    int lane = tid & 63, wid = tid >> 6;
    __shared__ int wsum[16];
    int cbase = c << 12;
    float4 sc = reinterpret_cast<const float4*>(scoresT + cbase)[tid];
    int f0 = sc.x > SCORE_TH, f1 = sc.y > SCORE_TH, f2 = sc.z > SCORE_TH, f3 = sc.w > SCORE_TH;
    int f = f0 + f1 + f2 + f3;
    int inc = f;
    for (int off = 1; off < 64; off <<= 1) {
        int o = __shfl_up(inc, off);
        if (lane >= off) inc += o;
    }
    if (lane == 63) wsum[wid] = inc;
    __syncthreads();
    int wbase = 0;
    for (int i = 0; i < wid; i++) wbase += wsum[i];
    int pos = wbase + inc - f;  // exclusive prefix
    int n0 = tid * 4;
    int fl[4] = {f0, f1, f2, f3};
    for (int d = 0; d < 4; d++) {
        if (fl[d]) {
            int n = n0 + d;
            validList[cbase + pos] = n;
            vBox[cbase + pos] = boxesT[cbase + n];
            vArea[cbase + pos] = areaT[cbase + n];
            pos++;
        }
    }
    if (tid == 1023) mVal[c] = wbase + inc;
}

// K3: triangular tiled rep-matrix over rank-compacted boxes. Block = (class,
// i-tile, j-tile<=i-tile), 128 threads (one i-rank each), j-tile staged in LDS,
// no-break min scan, one atomicMin per thread only when a match exists (rare).
__global__ void __launch_bounds__(128) k_repmat(const float4* __restrict__ vBox,
                                                const float* __restrict__ vArea,
                                                const int* __restrict__ mVal,
                                                int* minRank) {
    int bid = blockIdx.x;
    int c = bid / NTRI;
    int t = bid - c * NTRI;
    int ci = (int)((sqrtf(8.0f * (float)t + 1.0f) - 1.0f) * 0.5f);
    while ((ci + 1) * (ci + 2) / 2 <= t) ci++;
    while (ci * (ci + 1) / 2 > t) ci--;
    int cj = t - ci * (ci + 1) / 2;
    int mc = mVal[c];
    int ib = ci * TILE, jb = cj * TILE;
    if (ib >= mc || jb >= mc) return;
    int tid = threadIdx.x;
    int cbase = c << 12;
    __shared__ float4 sB[TILE];
    __shared__ float sA[TILE];
    if (jb + tid < mc) {
        sB[tid] = vBox[cbase + jb + tid];
        sA[tid] = vArea[cbase + jb + tid];
    }
    __syncthreads();
    int i = ib + tid;
    if (i >= mc) return;
    float4 bk = vBox[cbase + i];
    float ak = vArea[cbase + i];
    int limit = min(TILE, mc - jb);
    if (ci == cj) limit = min(limit, i - jb);  // strictly below diagonal
    int lmin = 0x7FFFFFFF;
    #pragma unroll 4
    for (int r = 0; r < limit; r++) {
        float ov = iou_f(bk, ak, sB[r], sA[r]);
        if (ov > IOU_TH && r < lmin) lmin = r;
    }
    if (lmin != 0x7FFFFFFF) atomicMin(&minRank[cbase + i], jb + lmin);
}

// K4 (cooperative, 128 blocks x 256 = CN threads):
// phase0 repfinal -> phase1 survscan+hist -> phase2 prefix (block 0)
// -> phase3 selgather -> phase4 sort (block 0) + out (blocks 1..100)
__global__ void __launch_bounds__(256) k_tail(const float4* __restrict__ boxesT,
                                              const float* __restrict__ areaT,
                                              const float* __restrict__ confT,
                                              const float* __restrict__ scoresT,
                                              const float* __restrict__ poses,
                                              const int* __restrict__ validList,
                                              const int* __restrict__ mVal,
                                              const float4* __restrict__ vBox,
                                              const float* __restrict__ vArea,
                                              const int* __restrict__ minRank,
                                              int* rep, int* surv, int* hist,
                                              int* blockCnt, int* blockOff,
                                              int* count_g, int* t0_g,
                                              int* sel, float* cand, int* gcnt,
                                              float* out) {
    cg::grid_group grid = cg::this_grid();
    int bid = blockIdx.x, tid = threadIdx.x;
    int lane = tid & 63, w = tid >> 6;
    int t = bid * 256 + tid;

    __shared__ int wcnt[4];
    __shared__ int sfx[256];
    __shared__ float sSort[CAND_CAP];
    __shared__ unsigned long long keyArr[4096];
    __shared__ int nmS;
    __shared__ int kselS[KSEL];
    __shared__ unsigned long long bestS;
    __shared__ unsigned long long redK[4];

    // ---- phase 0: repfinal ----
    {
        int c = t >> 12;
        int i = t & (N_ANCH - 1);
        int mc = mVal[c];
        if (i < mc) {
            int cbase = c << 12;
            int k = validList[cbase + i];
            int mr = minRank[cbase + i];
            if (mr > i) mr = i;  // self
            int j = validList[cbase + mr];
            rep[cbase + k] = j;
            if (mr < i) {
                float ov = iou_f(vBox[cbase + i], vArea[cbase + i],
                                 vBox[cbase + mr], vArea[cbase + mr]);
                float bcv = (1.0f - ov) * confT[cbase + k];
                if (bcv != 0.0f) surv[cbase + j] = 1;  // benign same-value race
            }
        }
    }
    __threadfence();
    grid.sync();

    // ---- phase 1: survivor counts + score histogram ----
    {
        int flag = surv[t] != 0;
        unsigned long long mask = __ballot(flag);
        if (lane == 0) wcnt[w] = __popcll(mask);
        if (flag) {
            unsigned bits = __float_as_uint(scoresT[t]);
            int bb = (int)((bits - 0x3F000000u) >> 13);
            int bkt = bb < 0 ? 0 : (bb > 1023 ? 1023 : bb);
            atomicAdd(&hist[bkt], 1);
        }
        __syncthreads();
        if (tid == 0) blockCnt[bid] = wcnt[0] + wcnt[1] + wcnt[2] + wcnt[3];
    }
    __threadfence();
    grid.sync();

    // ---- phase 2: prefix + histogram threshold (block 0) ----
    if (bid == 0) {
        __shared__ int thrB;
        __shared__ int countS;
        if (tid == 0) {
            int run = 0;
            for (int i = 0; i < 128; i++) { blockOff[i] = run; run += blockCnt[i]; }
            *count_g = run; countS = run; thrB = 0;
        }
        int part = hist[4 * tid] + hist[4 * tid + 1] + hist[4 * tid + 2] + hist[4 * tid + 3];
        sfx[tid] = part;
        __syncthreads();
        if (tid == 0) {
            int run = 0;
            for (int i = 255; i >= 0; i--) { int v = sfx[i]; sfx[i] = run; run += v; }
        }
        __syncthreads();
        int count = countS;
        int target = count < MAX_DET ? count : MAX_DET;
        int S = sfx[tid];
        int found = -1;
        for (int b = 4 * tid + 3; b >= 4 * tid; b--) {
            S += hist[b];
            if (found < 0 && S >= target) found = b;
        }
        if (found >= 0) atomicMax(&thrB, found);
        __syncthreads();
        if (tid == 0) *t0_g = thrB;
    }
    __threadfence();
    grid.sync();

    // ---- phase 3: ordered sel-write + candidate gather ----
    {
        int flag = surv[t] != 0;
        unsigned long long mask = __ballot(flag);
        if (lane == 0) wcnt[w] = __popcll(mask);
        __syncthreads();
        int rank = __popcll(mask & ((1ull << lane) - 1ull));
        int wbase = 0;
        for (int i = 0; i < w; i++) wbase += wcnt[i];
        int idx = blockOff[bid] + wbase + rank;
        if (flag && idx < MAX_DET) sel[idx] = t;
        if (flag) {
            unsigned bits = __float_as_uint(scoresT[t]);
            int bb = (int)((bits - 0x3F000000u) >> 13);
            int bkt = bb < 0 ? 0 : (bb > 1023 ? 1023 : bb);
            if (bkt >= *t0_g) {
                int id = atomicAdd(gcnt, 1);
                if (id < CAND_CAP) cand[id] = scoresT[t];
            }
        }
    }
    __threadfence();
    grid.sync();

    // ---- phase 4: sort (block 0) / per-slot outputs (blocks 1..100) ----
    int count = *count_g;
    if (bid == 0) {
        int cc = *gcnt; if (cc > CAND_CAP) cc = CAND_CAP;
        int n = 128; while (n < cc) n <<= 1;
        for (int i = tid; i < n; i += 256) sSort[i] = (i < cc) ? -cand[i] : 1e38f;
        __syncthreads();
        for (int kk = 2; kk <= n; kk <<= 1) {
            for (int jj = kk >> 1; jj > 0; jj >>= 1) {
                for (int i = tid; i < n; i += 256) {
                    int ixj = i ^ jj;
                    if (ixj > i) {
                        float a = sSort[i], b2 = sSort[ixj];
                        bool up = ((i & kk) == 0);
                        if (up ? (a > b2) : (a < b2)) { sSort[i] = b2; sSort[ixj] = a; }
                    }
                }
                __syncthreads();
            }
        }
        if (tid < MAX_DET) out[tid] = (tid < count) ? -sSort[tid] : -1.0f;
    } else if (bid <= MAX_DET) {
        int s = bid - 1;
        if (s >= count) {
            if (tid == 0) { out[100 + s] = -1.0f; out[1400 + s] = -1.0f; }
            if (tid < 12) out[200 + s * 12 + tid] = -1.0f;
            if (tid >= 16 && tid < 20) out[1500 + s * 4 + (tid - 16)] = -1.0f;
        } else {
            int p = sel[s];
            int c = p >> 12;
            int r = p & (N_ANCH - 1);
            int cbase = c << 12;
            if (tid == 0) nmS = 0;
            __syncthreads();
            float4 br = boxesT[cbase + r];
            float ar = areaT[cbase + r];
            for (int k = tid; k < N_ANCH; k += 256) {
                int rp = rep[cbase + k];  // poison/unwritten is negative -> no match
                if (rp == r && k != r) {
                    float ov = iou_f(br, ar, boxesT[cbase + k], areaT[cbase + k]);
                    float bcv = (1.0f - ov) * confT[cbase + k];
                    if (bcv != 0.0f) {
                        int id = atomicAdd(&nmS, 1);
                        keyArr[id] = ((unsigned long long)__float_as_uint(bcv) << 32) | (unsigned)k;
                    }
                }
            }
            __syncthreads();
            int nm = nmS;
            int dn = nm < KSEL ? nm : KSEL;
            unsigned long long lastBest = ~0ull;
            for (int j = 0; j < dn; j++) {
                unsigned long long bk = ~0ull;
                for (int i = tid; i < nm; i += 256) {
                    unsigned long long v = keyArr[i];
                    if (v == lastBest) { keyArr[i] = ~0ull; v = ~0ull; }
                    if (v < bk) bk = v;
                }
                for (int off = 32; off > 0; off >>= 1) {
                    unsigned long long o = __shfl_down(bk, off);
                    if (o < bk) bk = o;
                }
                if (lane == 0) redK[w] = bk;
                __syncthreads();
                if (tid == 0) {
                    unsigned long long B = redK[0];
                    for (int q2 = 1; q2 < 4; q2++) if (redK[q2] < B) B = redK[q2];
                    bestS = B;
                    kselS[j] = (int)(B & 0xFFFFFFFFull);
                }
                __syncthreads();
                lastBest = bestS;
            }
            float fdn = (float)(dn > 0 ? dn : 1);
            if (tid < 12) {
                float ssum = 0.0f;
                for (int j = 0; j < dn; j++) {
                    int k = kselS[j];
                    ssum += poses[(k * 8 + c) * 12 + tid];
                }
                out[200 + s * 12 + tid] = ssum / fdn;
            } else if (tid < 16) {
                int d = tid - 12;
                float ssum = 0.0f;
                for (int j = 0; j < dn; j++) {
                    int k = kselS[j];
                    const float* bb = (const float*)&boxesT[cbase + k];
                    ssum += bb[d];
                }
                out[1500 + s * 4 + d] = ssum / fdn;
            } else if (tid == 16) {
                out[100 + s] = (float)c;
            } else if (tid == 17) {
                out[1400 + s] = (float)r;
            }
        }
    }
}

extern "C" void kernel_launch(void* const* d_in, const int* in_sizes, int n_in,
                              void* d_out, int out_size, void* d_ws, size_t ws_size,
                              hipStream_t stream) {
    const float* boxes = (const float*)d_in[1];
    const float* cls   = (const float*)d_in[2];
    const float* poses = (const float*)d_in[3];
    const float* conf  = (const float*)d_in[4];
    float* out = (float*)d_out;

    char* ws = (char*)d_ws;
    size_t off = 0;
    auto alloc = [&](size_t bytes) {
        void* p = ws + off;
        off += (bytes + 255) & ~(size_t)255;
        return p;
    };
    float4* boxesT  = (float4*)alloc(CN * sizeof(float4));
    float*  areaT   = (float*)alloc(CN * sizeof(float));
    float*  scoresT = (float*)alloc(CN * sizeof(float));
    float*  confT   = (float*)alloc(CN * sizeof(float));
    int*    validList = (int*)alloc(CN * sizeof(int));
    float4* vBox    = (float4*)alloc(CN * sizeof(float4));
    float*  vArea   = (float*)alloc(CN * sizeof(float));
    int*    mVal    = (int*)alloc(64);
    int*    rep     = (int*)alloc(CN * sizeof(int));
    int*    surv    = (int*)alloc(CN * sizeof(int));
    int*    sel     = (int*)alloc(MAX_DET * sizeof(int));
    int*    count_g = (int*)alloc(64);
    float*  cand    = (float*)alloc(CAND_CAP * sizeof(float));
    int*    hist    = (int*)alloc(1024 * sizeof(int));
    int*    blockCnt = (int*)alloc(128 * sizeof(int));
    int*    blockOff = (int*)alloc(128 * sizeof(int));
    int*    t0_g    = (int*)alloc(64);
    int*    gcnt    = (int*)alloc(64);
    int*    minRank = (int*)alloc(CN * sizeof(int));

    k_prep<<<CN / 256, 256, 0, stream>>>(boxes, cls, conf, boxesT, areaT, scoresT, confT,
                                         surv, hist, gcnt, minRank);
    k_validlist<<<NCLS, 1024, 0, stream>>>(scoresT, boxesT, areaT, validList, vBox, vArea, mVal);
    k_repmat<<<NCLS * NTRI, 128, 0, stream>>>(vBox, vArea, mVal, minRank);

    void* args[] = {
        (void*)&boxesT, (void*)&areaT, (void*)&confT, (void*)&scoresT, (void*)&poses,
        (void*)&validList, (void*)&mVal, (void*)&vBox, (void*)&vArea, (void*)&minRank,
        (void*)&rep, (void*)&surv, (void*)&hist, (void*)&blockCnt, (void*)&blockOff,
        (void*)&count_g, (void*)&t0_g, (void*)&sel, (void*)&cand, (void*)&gcnt,
        (void*)&out
    };
    hipLaunchCooperativeKernel((void*)k_tail, dim3(128), dim3(256), args, 0, stream);
}

// Round 5
// 147.871 us; speedup vs baseline: 1.6945x; 1.6945x over previous
//
#include <hip/hip_runtime.h>
#include <stdint.h>

#define N_ANCH 4096
#define NCLS 8
#define CN (N_ANCH * NCLS)
#define SCORE_TH 0.5f
#define IOU_TH 0.5f
#define KSEL 11
#define MAX_DET 100
#define CAND_CAP 4096
#define TILE 128
#define TPC (N_ANCH / TILE)          // 32 i/j tiles per class (worst case)
#define NTRI (TPC * (TPC + 1) / 2)   // 528 triangular tiles per class

__device__ __forceinline__ float iou_f(float4 a, float areaA, float4 b, float areaB) {
    float x1 = fmaxf(a.x, b.x);
    float y1 = fmaxf(a.y, b.y);
    float x2 = fminf(a.z, b.z);
    float y2 = fminf(a.w, b.w);
    float wid = x2 - x1 + 1.0f;
    float hei = y2 - y1 + 1.0f;
    float inter = wid * hei;
    float den = areaA + areaB - inter;
    float ov = (den == 0.0f) ? 0.0f : (inter / den);
    if (wid <= 0.0f || hei <= 0.0f) ov = 0.0f;
    return ov;
}

// K1 (8 blocks x 1024): transpose + areas + init + per-class valid compaction.
// One block per class; thread tid handles anchors tid*4..tid*4+3 (order needed
// for the ordered prefix compaction).
__global__ void __launch_bounds__(1024) k_prep_valid(const float* __restrict__ boxes,
                                                     const float* __restrict__ cls,
                                                     const float* __restrict__ conf,
                                                     float4* boxesT, float* areaT,
                                                     float* scoresT, float* confT,
                                                     int* validList, float4* vBox,
                                                     float* vArea, int* mVal,
                                                     int* surv, int* minRank, int* hist) {
    int c = blockIdx.x;
    int tid = threadIdx.x;
    int lane = tid & 63, wid = tid >> 6;
    __shared__ int wsum[16];
    int cbase = c << 12;
    int n0 = tid * 4;
    const float4* boxes4 = reinterpret_cast<const float4*>(boxes);
    float4 b[4]; float s[4], cf[4], ar[4];
    #pragma unroll
    for (int d = 0; d < 4; d++) {
        int src = (n0 + d) * 8 + c;
        s[d] = cls[src];
        cf[d] = conf[src];
        b[d] = boxes4[src];
        ar[d] = (b[d].z - b[d].x + 1.0f) * (b[d].w - b[d].y + 1.0f);
    }
    reinterpret_cast<float4*>(scoresT + cbase)[tid] = make_float4(s[0], s[1], s[2], s[3]);
    reinterpret_cast<float4*>(confT + cbase)[tid] = make_float4(cf[0], cf[1], cf[2], cf[3]);
    reinterpret_cast<float4*>(areaT + cbase)[tid] = make_float4(ar[0], ar[1], ar[2], ar[3]);
    #pragma unroll
    for (int d = 0; d < 4; d++) boxesT[cbase + n0 + d] = b[d];
    reinterpret_cast<int4*>(surv + cbase)[tid] = make_int4(0, 0, 0, 0);
    reinterpret_cast<int4*>(minRank + cbase)[tid] =
        make_int4(0x7FFFFFFF, 0x7FFFFFFF, 0x7FFFFFFF, 0x7FFFFFFF);
    if (c == 0) hist[tid] = 0;
    // ---- ordered compaction ----
    int f0 = s[0] > SCORE_TH, f1 = s[1] > SCORE_TH, f2 = s[2] > SCORE_TH, f3 = s[3] > SCORE_TH;
    int f = f0 + f1 + f2 + f3;
    int inc = f;
    for (int off = 1; off < 64; off <<= 1) {
        int o = __shfl_up(inc, off);
        if (lane >= off) inc += o;
    }
    if (lane == 63) wsum[wid] = inc;
    __syncthreads();
    int wbase = 0;
    for (int i = 0; i < wid; i++) wbase += wsum[i];
    int pos = wbase + inc - f;  // exclusive prefix
    int fl[4] = {f0, f1, f2, f3};
    #pragma unroll
    for (int d = 0; d < 4; d++) {
        if (fl[d]) {
            validList[cbase + pos] = n0 + d;
            vBox[cbase + pos] = b[d];
            vArea[cbase + pos] = ar[d];
            pos++;
        }
    }
    if (tid == 1023) mVal[c] = wbase + inc;
}

// K2: triangular tiled rep-matrix over rank-compacted boxes.
__global__ void __launch_bounds__(128) k_repmat(const float4* __restrict__ vBox,
                                                const float* __restrict__ vArea,
                                                const int* __restrict__ mVal,
                                                int* minRank) {
    int bid = blockIdx.x;
    int c = bid / NTRI;
    int t = bid - c * NTRI;
    int ci = (int)((sqrtf(8.0f * (float)t + 1.0f) - 1.0f) * 0.5f);
    while ((ci + 1) * (ci + 2) / 2 <= t) ci++;
    while (ci * (ci + 1) / 2 > t) ci--;
    int cj = t - ci * (ci + 1) / 2;
    int mc = mVal[c];
    int ib = ci * TILE, jb = cj * TILE;
    if (ib >= mc || jb >= mc) return;
    int tid = threadIdx.x;
    int cbase = c << 12;
    __shared__ float4 sB[TILE];
    __shared__ float sA[TILE];
    if (jb + tid < mc) {
        sB[tid] = vBox[cbase + jb + tid];
        sA[tid] = vArea[cbase + jb + tid];
    }
    __syncthreads();
    int i = ib + tid;
    if (i >= mc) return;
    float4 bk = vBox[cbase + i];
    float ak = vArea[cbase + i];
    int limit = min(TILE, mc - jb);
    if (ci == cj) limit = min(limit, i - jb);  // strictly below diagonal
    int lmin = 0x7FFFFFFF;
    #pragma unroll 4
    for (int r = 0; r < limit; r++) {
        float ov = iou_f(bk, ak, sB[r], sA[r]);
        if (ov > IOU_TH && r < lmin) lmin = r;
    }
    if (lmin != 0x7FFFFFFF) atomicMin(&minRank[cbase + i], jb + lmin);
}

// K3: finalize rep + surv from minRank
__global__ void __launch_bounds__(256) k_repA(const float4* __restrict__ vBox,
                                              const float* __restrict__ vArea,
                                              const float* __restrict__ confT,
                                              const int* __restrict__ validList,
                                              const int* __restrict__ mVal,
                                              const int* __restrict__ minRank,
                                              int* rep, int* surv) {
    int t = blockIdx.x * 256 + threadIdx.x;
    int c = t >> 12;
    int i = t & (N_ANCH - 1);
    int mc = mVal[c];
    if (i >= mc) return;
    int cbase = c << 12;
    int k = validList[cbase + i];
    int mr = minRank[cbase + i];
    if (mr > i) mr = i;  // self
    int j = validList[cbase + mr];
    rep[cbase + k] = j;
    if (mr < i) {
        float ov = iou_f(vBox[cbase + i], vArea[cbase + i], vBox[cbase + mr], vArea[cbase + mr]);
        float bcv = (1.0f - ov) * confT[cbase + k];
        if (bcv != 0.0f) surv[cbase + j] = 1;  // benign same-value race
    }
}

// K4: per-block ordered survivor compaction into candPos/candScore + counts + hist
__global__ void __launch_bounds__(256) k_B(const int* __restrict__ surv,
                                           const float* __restrict__ scoresT,
                                           int* candPos, float* candScore,
                                           int* blockCnt, int* hist) {
    int bid = blockIdx.x, tid = threadIdx.x;
    int lane = tid & 63, w = tid >> 6;
    int t = bid * 256 + tid;
    int flag = surv[t] != 0;
    unsigned long long mask = __ballot(flag);
    __shared__ int wcnt[4];
    if (lane == 0) wcnt[w] = __popcll(mask);
    __syncthreads();
    int rank = __popcll(mask & ((1ull << lane) - 1ull));
    int wbase = 0;
    for (int i = 0; i < w; i++) wbase += wcnt[i];
    if (flag) {
        int local = wbase + rank;
        float v = scoresT[t];
        candPos[bid * 256 + local] = t;
        candScore[bid * 256 + local] = v;
        unsigned bits = __float_as_uint(v);
        int bb = (int)((bits - 0x3F000000u) >> 13);
        int bkt = bb < 0 ? 0 : (bb > 1023 ? 1023 : bb);
        atomicAdd(&hist[bkt], 1);
    }
    if (tid == 0) blockCnt[bid] = wcnt[0] + wcnt[1] + wcnt[2] + wcnt[3];
}

// K5 (single block, 1024): prefix, sel (first-100 flat order), histogram
// threshold, candidate gather, bitonic top-100 scores.
__global__ void __launch_bounds__(1024) k_C(const int* __restrict__ blockCnt,
                                            const int* __restrict__ hist,
                                            const int* __restrict__ candPos,
                                            const float* __restrict__ candScore,
                                            int* sel, int* count_g, float* out) {
    int tid = threadIdx.x;
    __shared__ int bc[128];
    __shared__ int offS[129];
    __shared__ int sfx[256];
    __shared__ int thrB;
    __shared__ int ccS;
    __shared__ float sc[CAND_CAP];
    if (tid < 128) bc[tid] = blockCnt[tid];
    if (tid == 0) { thrB = 0; ccS = 0; }
    __syncthreads();
    if (tid == 0) {
        int run = 0;
        for (int i = 0; i < 128; i++) { offS[i] = run; run += bc[i]; }
        offS[128] = run;
        *count_g = run;
    }
    __syncthreads();
    int count = offS[128];
    int target = count < MAX_DET ? count : MAX_DET;
    if (tid < target) {
        int lo = 0, hi = 127;
        while (lo < hi) { int mid = (lo + hi + 1) >> 1; if (offS[mid] <= tid) lo = mid; else hi = mid - 1; }
        sel[tid] = candPos[lo * 256 + (tid - offS[lo])];
    }
    if (tid < 256) {
        sfx[tid] = hist[4 * tid] + hist[4 * tid + 1] + hist[4 * tid + 2] + hist[4 * tid + 3];
    }
    __syncthreads();
    if (tid == 0) {
        int run = 0;
        for (int i = 255; i >= 0; i--) { int v = sfx[i]; sfx[i] = run; run += v; }
    }
    __syncthreads();
    if (tid < 256) {
        int S = sfx[tid];
        int found = -1;
        for (int b = 4 * tid + 3; b >= 4 * tid; b--) {
            S += hist[b];
            if (found < 0 && S >= target) found = b;
        }
        if (found >= 0) atomicMax(&thrB, found);
    }
    __syncthreads();
    int t0 = thrB;
    for (int pos = tid; pos < CN; pos += 1024) {
        int b = pos >> 8, l = pos & 255;
        if (l < bc[b]) {
            float v = candScore[pos];
            unsigned bits = __float_as_uint(v);
            int bb = (int)((bits - 0x3F000000u) >> 13);
            int bkt = bb < 0 ? 0 : (bb > 1023 ? 1023 : bb);
            if (bkt >= t0) {
                int id = atomicAdd(&ccS, 1);
                if (id < CAND_CAP) sc[id] = -v;
            }
        }
    }
    __syncthreads();
    int cc = ccS; if (cc > CAND_CAP) cc = CAND_CAP;
    int n = 128; while (n < cc) n <<= 1;
    for (int i = tid; i < n; i += 1024) if (i >= cc) sc[i] = 1e38f;
    __syncthreads();
    for (int kk = 2; kk <= n; kk <<= 1) {
        for (int jj = kk >> 1; jj > 0; jj >>= 1) {
            for (int i = tid; i < n; i += 1024) {
                int ixj = i ^ jj;
                if (ixj > i) {
                    float a = sc[i], b2 = sc[ixj];
                    bool up = ((i & kk) == 0);
                    if (up ? (a > b2) : (a < b2)) { sc[i] = b2; sc[ixj] = a; }
                }
            }
            __syncthreads();
        }
    }
    if (tid < MAX_DET) out[tid] = (tid < count) ? -sc[tid] : -1.0f;
}

// K6: one block per output slot — scan anchors for cluster members (rep==r),
// pick 11 smallest (bcv,k) keys, average poses/boxes; fill -1 past count.
__global__ void __launch_bounds__(256) k_out(const float4* __restrict__ boxesT,
                                             const float* __restrict__ areaT,
                                             const float* __restrict__ confT,
                                             const float* __restrict__ poses,
                                             const int* __restrict__ rep,
                                             const int* __restrict__ sel,
                                             const int* __restrict__ count_g,
                                             float* out) {
    int s = blockIdx.x;
    int tid = threadIdx.x;
    int lane = tid & 63, w = tid >> 6;
    int count = *count_g;
    if (s >= count) {
        if (tid == 0) { out[100 + s] = -1.0f; out[1400 + s] = -1.0f; }
        if (tid < 12) out[200 + s * 12 + tid] = -1.0f;
        if (tid >= 16 && tid < 20) out[1500 + s * 4 + (tid - 16)] = -1.0f;
        return;
    }
    int p = sel[s];
    int c = p >> 12;
    int r = p & (N_ANCH - 1);
    int cbase = c << 12;
    __shared__ unsigned long long keyArr[4096];
    __shared__ int nmS;
    __shared__ int kselS[KSEL];
    __shared__ unsigned long long bestS;
    __shared__ unsigned long long redK[4];
    if (tid == 0) nmS = 0;
    __syncthreads();
    float4 br = boxesT[cbase + r];
    float ar = areaT[cbase + r];
    for (int k = tid; k < N_ANCH; k += 256) {
        int rp = rep[cbase + k];  // unwritten entries hold poison (negative) -> no match
        if (rp == r && k != r) {
            float ov = iou_f(br, ar, boxesT[cbase + k], areaT[cbase + k]);
            float bcv = (1.0f - ov) * confT[cbase + k];
            if (bcv != 0.0f) {
                int id = atomicAdd(&nmS, 1);
                keyArr[id] = ((unsigned long long)__float_as_uint(bcv) << 32) | (unsigned)k;
            }
        }
    }
    __syncthreads();
    int nm = nmS;
    int dn = nm < KSEL ? nm : KSEL;
    unsigned long long lastBest = ~0ull;
    for (int j = 0; j < dn; j++) {
        unsigned long long bk = ~0ull;
        for (int i = tid; i < nm; i += 256) {
            unsigned long long v = keyArr[i];
            if (v == lastBest) { keyArr[i] = ~0ull; v = ~0ull; }
            if (v < bk) bk = v;
        }
        for (int off = 32; off > 0; off >>= 1) {
            unsigned long long o = __shfl_down(bk, off);
            if (o < bk) bk = o;
        }
        if (lane == 0) redK[w] = bk;
        __syncthreads();
        if (tid == 0) {
            unsigned long long B = redK[0];
            for (int q2 = 1; q2 < 4; q2++) if (redK[q2] < B) B = redK[q2];
            bestS = B;
            kselS[j] = (int)(B & 0xFFFFFFFFull);
        }
        __syncthreads();
        lastBest = bestS;
    }
    float fdn = (float)(dn > 0 ? dn : 1);
    if (tid < 12) {
        float ssum = 0.0f;
        for (int j = 0; j < dn; j++) ssum += poses[(kselS[j] * 8 + c) * 12 + tid];
        out[200 + s * 12 + tid] = ssum / fdn;
    } else if (tid < 16) {
        int d = tid - 12;
        float ssum = 0.0f;
        for (int j = 0; j < dn; j++) {
            const float* bb = (const float*)&boxesT[cbase + kselS[j]];
            ssum += bb[d];
        }
        out[1500 + s * 4 + d] = ssum / fdn;
    } else if (tid == 16) {
        out[100 + s] = (float)c;
    } else if (tid == 17) {
        out[1400 + s] = (float)r;
    }
}

extern "C" void kernel_launch(void* const* d_in, const int* in_sizes, int n_in,
                              void* d_out, int out_size, void* d_ws, size_t ws_size,
                              hipStream_t stream) {
    const float* boxes = (const float*)d_in[1];
    const float* cls   = (const float*)d_in[2];
    const float* poses = (const float*)d_in[3];
    const float* conf  = (const float*)d_in[4];
    float* out = (float*)d_out;

    char* ws = (char*)d_ws;
    size_t off = 0;
    auto alloc = [&](size_t bytes) {
        void* p = ws + off;
        off += (bytes + 255) & ~(size_t)255;
        return p;
    };
    float4* boxesT   = (float4*)alloc(CN * sizeof(float4));
    float*  areaT    = (float*)alloc(CN * sizeof(float));
    float*  scoresT  = (float*)alloc(CN * sizeof(float));
    float*  confT    = (float*)alloc(CN * sizeof(float));
    int*    validList= (int*)alloc(CN * sizeof(int));
    float4* vBox     = (float4*)alloc(CN * sizeof(float4));
    float*  vArea    = (float*)alloc(CN * sizeof(float));
    int*    mVal     = (int*)alloc(64);
    int*    rep      = (int*)alloc(CN * sizeof(int));
    int*    surv     = (int*)alloc(CN * sizeof(int));
    int*    minRank  = (int*)alloc(CN * sizeof(int));
    int*    sel      = (int*)alloc(MAX_DET * sizeof(int));
    int*    count_g  = (int*)alloc(64);
    int*    candPos  = (int*)alloc(CN * sizeof(int));
    float*  candScore= (float*)alloc(CN * sizeof(float));
    int*    hist     = (int*)alloc(1024 * sizeof(int));
    int*    blockCnt = (int*)alloc(128 * sizeof(int));

    k_prep_valid<<<NCLS, 1024, 0, stream>>>(boxes, cls, conf, boxesT, areaT, scoresT, confT,
                                            validList, vBox, vArea, mVal, surv, minRank, hist);
    k_repmat<<<NCLS * NTRI, 128, 0, stream>>>(vBox, vArea, mVal, minRank);
    k_repA<<<CN / 256, 256, 0, stream>>>(vBox, vArea, confT, validList, mVal, minRank, rep, surv);
    k_B<<<CN / 256, 256, 0, stream>>>(surv, scoresT, candPos, candScore, blockCnt, hist);
    k_C<<<1, 1024, 0, stream>>>(blockCnt, hist, candPos, candScore, sel, count_g, out);
    k_out<<<MAX_DET, 256, 0, stream>>>(boxesT, areaT, confT, poses, rep, sel, count_g, out);
}

// Round 6
// 139.043 us; speedup vs baseline: 1.8021x; 1.0635x over previous
//
#include <hip/hip_runtime.h>
#include <stdint.h>

#define N_ANCH 4096
#define NCLS 8
#define CN (N_ANCH * NCLS)
#define SCORE_TH 0.5f
#define IOU_TH 0.5f
#define KSEL 11
#define MAX_DET 100
#define CAND_CAP 4096
#define TILE 128
#define TPC (N_ANCH / TILE)          // 32 i/j tiles per class (worst case)
#define NTRI (TPC * (TPC + 1) / 2)   // 528 triangular tiles per class

__device__ __forceinline__ float iou_f(float4 a, float areaA, float4 b, float areaB) {
    float x1 = fmaxf(a.x, b.x);
    float y1 = fmaxf(a.y, b.y);
    float x2 = fminf(a.z, b.z);
    float y2 = fminf(a.w, b.w);
    float wid = x2 - x1 + 1.0f;
    float hei = y2 - y1 + 1.0f;
    float inter = wid * hei;
    float den = areaA + areaB - inter;
    float ov = (den == 0.0f) ? 0.0f : (inter / den);
    if (wid <= 0.0f || hei <= 0.0f) ov = 0.0f;
    return ov;
}

// K1a (128 blocks x 256): coalesced reads of inputs, scatter-write transposed
// SoA + areas, init surv/minRank/hist. (Round-5 lesson: the 8-block fused
// version gathered at 128B lane stride -> ~40us. Coalesced reads here.)
__global__ void __launch_bounds__(256) k_prep(const float* __restrict__ boxes,
                                              const float* __restrict__ cls,
                                              const float* __restrict__ conf,
                                              float4* boxesT, float* areaT,
                                              float* scoresT, float* confT,
                                              int* surv, int* minRank, int* hist) {
    int t = blockIdx.x * 256 + threadIdx.x;
    int n = t >> 3;  // anchor
    int c = t & 7;   // class
    int p = (c << 12) + n;
    scoresT[p] = cls[t];
    confT[p] = conf[t];
    float4 b = reinterpret_cast<const float4*>(boxes)[t];
    boxesT[p] = b;
    areaT[p] = (b.z - b.x + 1.0f) * (b.w - b.y + 1.0f);
    surv[t] = 0;
    minRank[t] = 0x7FFFFFFF;
    if (t < 1024) hist[t] = 0;
}

// K1b (8 blocks x 1024): single-pass per-class compaction. Reads transposed
// scores coalesced (float4), emits rank-compacted vBox/vArea/vConf (gathers
// hit L2 - boxesT just written).
__global__ void __launch_bounds__(1024) k_validlist(const float* __restrict__ scoresT,
                                                    const float4* __restrict__ boxesT,
                                                    const float* __restrict__ areaT,
                                                    const float* __restrict__ confT,
                                                    int* validList, float4* vBox,
                                                    float* vArea, float* vConf, int* mVal) {
    int c = blockIdx.x;
    int tid = threadIdx.x;
    int lane = tid & 63, wid = tid >> 6;
    __shared__ int wsum[16];
    int cbase = c << 12;
    float4 sc = reinterpret_cast<const float4*>(scoresT + cbase)[tid];
    int f0 = sc.x > SCORE_TH, f1 = sc.y > SCORE_TH, f2 = sc.z > SCORE_TH, f3 = sc.w > SCORE_TH;
    int f = f0 + f1 + f2 + f3;
    int inc = f;
    for (int off = 1; off < 64; off <<= 1) {
        int o = __shfl_up(inc, off);
        if (lane >= off) inc += o;
    }
    if (lane == 63) wsum[wid] = inc;
    __syncthreads();
    int wbase = 0;
    for (int i = 0; i < wid; i++) wbase += wsum[i];
    int pos = wbase + inc - f;  // exclusive prefix
    int n0 = tid * 4;
    int fl[4] = {f0, f1, f2, f3};
    #pragma unroll
    for (int d = 0; d < 4; d++) {
        if (fl[d]) {
            int n = n0 + d;
            validList[cbase + pos] = n;
            vBox[cbase + pos] = boxesT[cbase + n];
            vArea[cbase + pos] = areaT[cbase + n];
            vConf[cbase + pos] = confT[cbase + n];
            pos++;
        }
    }
    if (tid == 1023) mVal[c] = wbase + inc;
}

// K2: triangular tiled rep-matrix over rank-compacted boxes. Block = (class,
// i-tile, j-tile<=i-tile), 128 threads (one i-rank each), j-tile staged in LDS,
// no-break min scan, one atomicMin per thread only when a match exists (rare).
__global__ void __launch_bounds__(128) k_repmat(const float4* __restrict__ vBox,
                                                const float* __restrict__ vArea,
                                                const int* __restrict__ mVal,
                                                int* minRank) {
    int bid = blockIdx.x;
    int c = bid / NTRI;
    int t = bid - c * NTRI;
    int ci = (int)((sqrtf(8.0f * (float)t + 1.0f) - 1.0f) * 0.5f);
    while ((ci + 1) * (ci + 2) / 2 <= t) ci++;
    while (ci * (ci + 1) / 2 > t) ci--;
    int cj = t - ci * (ci + 1) / 2;
    int mc = mVal[c];
    int ib = ci * TILE, jb = cj * TILE;
    if (ib >= mc || jb >= mc) return;
    int tid = threadIdx.x;
    int cbase = c << 12;
    __shared__ float4 sB[TILE];
    __shared__ float sA[TILE];
    if (jb + tid < mc) {
        sB[tid] = vBox[cbase + jb + tid];
        sA[tid] = vArea[cbase + jb + tid];
    }
    __syncthreads();
    int i = ib + tid;
    if (i >= mc) return;
    float4 bk = vBox[cbase + i];
    float ak = vArea[cbase + i];
    int limit = min(TILE, mc - jb);
    if (ci == cj) limit = min(limit, i - jb);  // strictly below diagonal
    int lmin = 0x7FFFFFFF;
    #pragma unroll 4
    for (int r = 0; r < limit; r++) {
        float ov = iou_f(bk, ak, sB[r], sA[r]);
        if (ov > IOU_TH && r < lmin) lmin = r;
    }
    if (lmin != 0x7FFFFFFF) atomicMin(&minRank[cbase + i], jb + lmin);
}

// K3: finalize rep + surv from minRank (coalesced over ranks)
__global__ void __launch_bounds__(256) k_repA(const float4* __restrict__ vBox,
                                              const float* __restrict__ vArea,
                                              const float* __restrict__ vConf,
                                              const int* __restrict__ validList,
                                              const int* __restrict__ mVal,
                                              const int* __restrict__ minRank,
                                              int* rep, int* surv) {
    int t = blockIdx.x * 256 + threadIdx.x;
    int c = t >> 12;
    int i = t & (N_ANCH - 1);
    int mc = mVal[c];
    if (i >= mc) return;
    int cbase = c << 12;
    int k = validList[cbase + i];
    int mr = minRank[cbase + i];
    if (mr > i) mr = i;  // self
    int j = validList[cbase + mr];
    rep[cbase + k] = j;
    if (mr < i) {
        float ov = iou_f(vBox[cbase + i], vArea[cbase + i], vBox[cbase + mr], vArea[cbase + mr]);
        float bcv = (1.0f - ov) * vConf[cbase + i];
        if (bcv != 0.0f) surv[cbase + j] = 1;  // benign same-value race
    }
}

// K4: per-block ordered survivor compaction into candPos/candScore + counts + hist
__global__ void __launch_bounds__(256) k_B(const int* __restrict__ surv,
                                           const float* __restrict__ scoresT,
                                           int* candPos, float* candScore,
                                           int* blockCnt, int* hist) {
    int bid = blockIdx.x, tid = threadIdx.x;
    int lane = tid & 63, w = tid >> 6;
    int t = bid * 256 + tid;
    int flag = surv[t] != 0;
    unsigned long long mask = __ballot(flag);
    __shared__ int wcnt[4];
    if (lane == 0) wcnt[w] = __popcll(mask);
    __syncthreads();
    int rank = __popcll(mask & ((1ull << lane) - 1ull));
    int wbase = 0;
    for (int i = 0; i < w; i++) wbase += wcnt[i];
    if (flag) {
        int local = wbase + rank;
        float v = scoresT[t];
        candPos[bid * 256 + local] = t;
        candScore[bid * 256 + local] = v;
        unsigned bits = __float_as_uint(v);
        int bb = (int)((bits - 0x3F000000u) >> 13);
        int bkt = bb < 0 ? 0 : (bb > 1023 ? 1023 : bb);
        atomicAdd(&hist[bkt], 1);
    }
    if (tid == 0) blockCnt[bid] = wcnt[0] + wcnt[1] + wcnt[2] + wcnt[3];
}

// K5 (single block, 1024): prefix, sel (first-100 flat order), histogram
// threshold, candidate gather, bitonic top-100 scores.
__global__ void __launch_bounds__(1024) k_C(const int* __restrict__ blockCnt,
                                            const int* __restrict__ hist,
                                            const int* __restrict__ candPos,
                                            const float* __restrict__ candScore,
                                            int* sel, int* count_g, float* out) {
    int tid = threadIdx.x;
    __shared__ int bc[128];
    __shared__ int offS[129];
    __shared__ int sfx[256];
    __shared__ int thrB;
    __shared__ int ccS;
    __shared__ float sc[CAND_CAP];
    if (tid < 128) bc[tid] = blockCnt[tid];
    if (tid == 0) { thrB = 0; ccS = 0; }
    __syncthreads();
    if (tid == 0) {
        int run = 0;
        for (int i = 0; i < 128; i++) { offS[i] = run; run += bc[i]; }
        offS[128] = run;
        *count_g = run;
    }
    __syncthreads();
    int count = offS[128];
    int target = count < MAX_DET ? count : MAX_DET;
    if (tid < target) {
        int lo = 0, hi = 127;
        while (lo < hi) { int mid = (lo + hi + 1) >> 1; if (offS[mid] <= tid) lo = mid; else hi = mid - 1; }
        sel[tid] = candPos[lo * 256 + (tid - offS[lo])];
    }
    if (tid < 256) {
        sfx[tid] = hist[4 * tid] + hist[4 * tid + 1] + hist[4 * tid + 2] + hist[4 * tid + 3];
    }
    __syncthreads();
    if (tid == 0) {
        int run = 0;
        for (int i = 255; i >= 0; i--) { int v = sfx[i]; sfx[i] = run; run += v; }
    }
    __syncthreads();
    if (tid < 256) {
        int S = sfx[tid];
        int found = -1;
        for (int b = 4 * tid + 3; b >= 4 * tid; b--) {
            S += hist[b];
            if (found < 0 && S >= target) found = b;
        }
        if (found >= 0) atomicMax(&thrB, found);
    }
    __syncthreads();
    int t0 = thrB;
    for (int pos = tid; pos < CN; pos += 1024) {
        int b = pos >> 8, l = pos & 255;
        if (l < bc[b]) {
            float v = candScore[pos];
            unsigned bits = __float_as_uint(v);
            int bb = (int)((bits - 0x3F000000u) >> 13);
            int bkt = bb < 0 ? 0 : (bb > 1023 ? 1023 : bb);
            if (bkt >= t0) {
                int id = atomicAdd(&ccS, 1);
                if (id < CAND_CAP) sc[id] = -v;
            }
        }
    }
    __syncthreads();
    int cc = ccS; if (cc > CAND_CAP) cc = CAND_CAP;
    int n = 128; while (n < cc) n <<= 1;
    for (int i = tid; i < n; i += 1024) if (i >= cc) sc[i] = 1e38f;
    __syncthreads();
    for (int kk = 2; kk <= n; kk <<= 1) {
        for (int jj = kk >> 1; jj > 0; jj >>= 1) {
            for (int i = tid; i < n; i += 1024) {
                int ixj = i ^ jj;
                if (ixj > i) {
                    float a = sc[i], b2 = sc[ixj];
                    bool up = ((i & kk) == 0);
                    if (up ? (a > b2) : (a < b2)) { sc[i] = b2; sc[ixj] = a; }
                }
            }
            __syncthreads();
        }
    }
    if (tid < MAX_DET) out[tid] = (tid < count) ? -sc[tid] : -1.0f;
}

// K6: one block per output slot — scan anchors for cluster members (rep==r),
// pick KSEL smallest (bcv,k) keys (fast path: nm<=KSEL needs no selection),
// average poses/boxes; fill -1 past count.
__global__ void __launch_bounds__(256) k_out(const float4* __restrict__ boxesT,
                                             const float* __restrict__ areaT,
                                             const float* __restrict__ confT,
                                             const float* __restrict__ poses,
                                             const int* __restrict__ rep,
                                             const int* __restrict__ sel,
                                             const int* __restrict__ count_g,
                                             float* out) {
    int s = blockIdx.x;
    int tid = threadIdx.x;
    int lane = tid & 63, w = tid >> 6;
    int count = *count_g;
    if (s >= count) {
        if (tid == 0) { out[100 + s] = -1.0f; out[1400 + s] = -1.0f; }
        if (tid < 12) out[200 + s * 12 + tid] = -1.0f;
        if (tid >= 16 && tid < 20) out[1500 + s * 4 + (tid - 16)] = -1.0f;
        return;
    }
    int p = sel[s];
    int c = p >> 12;
    int r = p & (N_ANCH - 1);
    int cbase = c << 12;
    __shared__ unsigned long long keyArr[4096];
    __shared__ int nmS;
    __shared__ int kselS[KSEL];
    __shared__ unsigned long long bestS;
    __shared__ unsigned long long redK[4];
    if (tid == 0) nmS = 0;
    __syncthreads();
    float4 br = boxesT[cbase + r];
    float ar = areaT[cbase + r];
    for (int k = tid; k < N_ANCH; k += 256) {
        int rp = rep[cbase + k];  // unwritten entries hold poison (negative) -> no match
        if (rp == r && k != r) {
            float ov = iou_f(br, ar, boxesT[cbase + k], areaT[cbase + k]);
            float bcv = (1.0f - ov) * confT[cbase + k];
            if (bcv != 0.0f) {
                int id = atomicAdd(&nmS, 1);
                keyArr[id] = ((unsigned long long)__float_as_uint(bcv) << 32) | (unsigned)k;
            }
        }
    }
    __syncthreads();
    int nm = nmS;
    int dn = nm < KSEL ? nm : KSEL;
    if (nm > KSEL) {
        // selection needed: 11 serial argmin rounds (rare path)
        unsigned long long lastBest = ~0ull;
        for (int j = 0; j < KSEL; j++) {
            unsigned long long bk = ~0ull;
            for (int i = tid; i < nm; i += 256) {
                unsigned long long v = keyArr[i];
                if (v == lastBest) { keyArr[i] = ~0ull; v = ~0ull; }
                if (v < bk) bk = v;
            }
            for (int off = 32; off > 0; off >>= 1) {
                unsigned long long o = __shfl_down(bk, off);
                if (o < bk) bk = o;
            }
            if (lane == 0) redK[w] = bk;
            __syncthreads();
            if (tid == 0) {
                unsigned long long B = redK[0];
                for (int q2 = 1; q2 < 4; q2++) if (redK[q2] < B) B = redK[q2];
                bestS = B;
                kselS[j] = (int)(B & 0xFFFFFFFFull);
            }
            __syncthreads();
            lastBest = bestS;
        }
    } else if (tid < dn) {
        // fast path: every member selected, order irrelevant for the average
        kselS[tid] = (int)(keyArr[tid] & 0xFFFFFFFFull);
    }
    __syncthreads();
    float fdn = (float)(dn > 0 ? dn : 1);
    if (tid < 12) {
        float ssum = 0.0f;
        for (int j = 0; j < dn; j++) ssum += poses[(kselS[j] * 8 + c) * 12 + tid];
        out[200 + s * 12 + tid] = ssum / fdn;
    } else if (tid < 16) {
        int d = tid - 12;
        float ssum = 0.0f;
        for (int j = 0; j < dn; j++) {
            const float* bb = (const float*)&boxesT[cbase + kselS[j]];
            ssum += bb[d];
        }
        out[1500 + s * 4 + d] = ssum / fdn;
    } else if (tid == 16) {
        out[100 + s] = (float)c;
    } else if (tid == 17) {
        out[1400 + s] = (float)r;
    }
}

extern "C" void kernel_launch(void* const* d_in, const int* in_sizes, int n_in,
                              void* d_out, int out_size, void* d_ws, size_t ws_size,
                              hipStream_t stream) {
    const float* boxes = (const float*)d_in[1];
    const float* cls   = (const float*)d_in[2];
    const float* poses = (const float*)d_in[3];
    const float* conf  = (const float*)d_in[4];
    float* out = (float*)d_out;

    char* ws = (char*)d_ws;
    size_t off = 0;
    auto alloc = [&](size_t bytes) {
        void* p = ws + off;
        off += (bytes + 255) & ~(size_t)255;
        return p;
    };
    float4* boxesT   = (float4*)alloc(CN * sizeof(float4));
    float*  areaT    = (float*)alloc(CN * sizeof(float));
    float*  scoresT  = (float*)alloc(CN * sizeof(float));
    float*  confT    = (float*)alloc(CN * sizeof(float));
    int*    validList= (int*)alloc(CN * sizeof(int));
    float4* vBox     = (float4*)alloc(CN * sizeof(float4));
    float*  vArea    = (float*)alloc(CN * sizeof(float));
    float*  vConf    = (float*)alloc(CN * sizeof(float));
    int*    mVal     = (int*)alloc(64);
    int*    rep      = (int*)alloc(CN * sizeof(int));
    int*    surv     = (int*)alloc(CN * sizeof(int));
    int*    minRank  = (int*)alloc(CN * sizeof(int));
    int*    sel      = (int*)alloc(MAX_DET * sizeof(int));
    int*    count_g  = (int*)alloc(64);
    int*    candPos  = (int*)alloc(CN * sizeof(int));
    float*  candScore= (float*)alloc(CN * sizeof(float));
    int*    hist     = (int*)alloc(1024 * sizeof(int));
    int*    blockCnt = (int*)alloc(128 * sizeof(int));

    k_prep<<<CN / 256, 256, 0, stream>>>(boxes, cls, conf, boxesT, areaT, scoresT, confT,
                                         surv, minRank, hist);
    k_validlist<<<NCLS, 1024, 0, stream>>>(scoresT, boxesT, areaT, confT,
                                           validList, vBox, vArea, vConf, mVal);
    k_repmat<<<NCLS * NTRI, 128, 0, stream>>>(vBox, vArea, mVal, minRank);
    k_repA<<<CN / 256, 256, 0, stream>>>(vBox, vArea, vConf, validList, mVal, minRank, rep, surv);
    k_B<<<CN / 256, 256, 0, stream>>>(surv, scoresT, candPos, candScore, blockCnt, hist);
    k_C<<<1, 1024, 0, stream>>>(blockCnt, hist, candPos, candScore, sel, count_g, out);
    k_out<<<MAX_DET, 256, 0, stream>>>(boxesT, areaT, confT, poses, rep, sel, count_g, out);
}